// Round 14
// baseline (3891.445 us; speedup 1.0000x reference)
//
#include <hip/hip_runtime.h>
#include <hip/hip_fp16.h>
#include <stdint.h>

typedef _Float16 h8 __attribute__((ext_vector_type(8)));
typedef float f4 __attribute__((ext_vector_type(4)));

#define MFMA16(a,b,c) __builtin_amdgcn_mfma_f32_16x16x32_f16((a),(b),(c),0,0,0)

// ---------------- ws memory map (fixed offsets; ring size rs is runtime) ----
constexpr size_t XT_OFF = 0;                       // [256 t][8 kg][64 b][8h] fp16
constexpr size_t XT_BYTES = 256ull * 4096 * 2;     // 2 MB
constexpr size_t WSTRM_OFF = XT_OFF + XT_BYTES;    // [144 cu][13 s][8 nt][1KB]
constexpr size_t WSTRM_BYTES = 144ull * 106496;    // 14.6 MB
constexpr size_t PL_OFF = WSTRM_OFF + WSTRM_BYTES; // progL[672] plain (L2) per-wave flags
constexpr size_t PX_OFF = PL_OFF + 4096;           // progX[672] sc1 (L3) per-wave flags
constexpr size_t CNT_OFF = PX_OFF + 4096;          // xcd claim counters[8]
constexpr size_t DIAG_OFF = CNT_OFF + 64;
constexpr size_t HL_OFF = DIAG_OFF + 4032;         // plain h rings [10 L][rs][64KB]
// hx (sc1 rings, odd L) follows hl: hx_off = HL_OFF + 10*rs*65536
// flag index: (L*16 + cl)*4 + wv ; head: 640 + hd*4 + wv

// force a pointer into SGPRs (uniform) for inline-asm "s" operands
__device__ __forceinline__ const char* unif(const void* p) {
  uint64_t u = (uint64_t)p;
  uint32_t lo = __builtin_amdgcn_readfirstlane((uint32_t)u);
  uint32_t hi = __builtin_amdgcn_readfirstlane((uint32_t)(u >> 32));
  return (const char*)(((uint64_t)hi << 32) | lo);
}

// ---------------- asm helpers (hand-counted vmcnt stream) ----------------
__device__ __forceinline__ h8 gld16_p(const void* base, int voff) {
  h8 v; asm volatile("global_load_dwordx4 %0, %1, %2" : "=v"(v) : "v"(voff), "s"(base)); return v;
}
__device__ __forceinline__ h8 gld16_sc1(const void* base, int voff) {
  h8 v; asm volatile("global_load_dwordx4 %0, %1, %2 sc1" : "=v"(v) : "v"(voff), "s"(base)); return v;
}
__device__ __forceinline__ void gst16_p(const void* base, int voff, h8 v) {
  asm volatile("global_store_dwordx4 %0, %1, %2" :: "v"(voff), "v"(v), "s"(base) : "memory");
}
__device__ __forceinline__ void gst16_sc1(const void* base, int voff, h8 v) {
  asm volatile("global_store_dwordx4 %0, %1, %2 sc1" :: "v"(voff), "v"(v), "s"(base) : "memory");
}
#define WAITI(n) do { asm volatile("s_waitcnt vmcnt(" #n ")" ::: "memory"); \
                      __builtin_amdgcn_sched_barrier(0); } while (0)

__device__ __forceinline__ int ld_prog(const int* p) {
  return __hip_atomic_load(p, __ATOMIC_RELAXED, __HIP_MEMORY_SCOPE_AGENT);
}
// vL1 invalidate, self-draining so compiler waitcnt accounting stays valid
#define INV_L1() asm volatile("buffer_inv sc0\n\ts_waitcnt vmcnt(0)" ::: "memory")

__device__ __forceinline__ float sigm(float x) { return __fdividef(1.f, 1.f + __expf(-x)); }
__device__ __forceinline__ float tanh_f(float x) { return 1.f - __fdividef(2.f, __expf(2.f*x) + 1.f); }

// ---------------- prep kernels ----------------
__global__ __launch_bounds__(256) void zero_kernel(char* ws, int rs) {
  int i = blockIdx.x * 256 + threadIdx.x;
  if (i < 163840) {                       // hl slot 0 of each layer = h(-1) = 0
    int layer = i >> 14, w = i & 16383;
    ((int*)(ws + HL_OFF))[(size_t)layer * rs * 16384 + w] = 0;
  } else {
    int j = i - 163840;
    if (j < 672) ((int*)(ws + PL_OFF))[j] = -1;
    else if (j < 1344) ((int*)(ws + PX_OFF))[j - 672] = -1;
    else if (j < 1352) ((int*)(ws + CNT_OFF))[j - 1344] = 0;
    else if (j == 1352) ((int*)(ws + DIAG_OFF))[0] = 0;
  }
}

__global__ __launch_bounds__(256) void xprep_kernel(const float* __restrict__ X, char* ws) {
  int u = blockIdx.x * 256 + threadIdx.x;
  if (u >= 131072) return;
  int t = u >> 9, rem = u & 511, kg = rem >> 6, b = rem & 63;
  const float* src = X + ((size_t)b * 256 + t) * 64 + kg * 8;
  h8 v;
#pragma unroll
  for (int j = 0; j < 8; ++j) v[j] = (_Float16)src[j];
  *(h8*)(ws + XT_OFF + (size_t)u * 16) = v;
}

// pack streamed kt 4..16 (s=0..12) into per-lane fragment layout
__global__ __launch_bounds__(256) void wsprep_kernel(const float* __restrict__ Wih,
                                                     const float* __restrict__ Whh, char* ws) {
  int u = blockIdx.x * 256 + threadIdx.x;
  if (u >= 144 * 6656) return;
  int cu = u / 6656, rem = u % 6656;
  int s = rem / 512, rem2 = rem % 512;
  int nt = rem2 >> 6, l = rem2 & 63;
  int ppc = l >> 2, lgc = l & 3;
  int L = 1 + cu / 16, cl = cu % 16, hbase = cl * 32;
  int kt = 4 + s, k = kt * 32 + lgc * 8;
  int row = (nt & 3) * 512 + hbase + ((nt >> 2) << 4) + ppc;
  const float* src = (k < 512) ? (Wih + (size_t)(L - 1) * 1048576 + (size_t)row * 512 + k)
                               : (Whh + (size_t)L * 1048576 + (size_t)row * 512 + (k - 512));
  h8 v;
#pragma unroll
  for (int j = 0; j < 8; ++j) v[j] = (_Float16)src[j];
  uint32_t off = (uint32_t)(ppc * 64 + lgc * 16) ^ (uint32_t)((ppc & 7) << 4);
  *(h8*)(ws + WSTRM_OFF + (size_t)cu * 106496 + (size_t)s * 8192 + (size_t)nt * 1024 + off) = v;
}

// ---------------- main persistent kernel ----------------
#define KTRES(r, Areg) do {                                                     \
  _Pragma("unroll") for (int nt_ = 0; nt_ < 8; ++nt_) {                         \
    h8 bv_ = *(const h8*)(lds + ((((r) * 8 + nt_) << 10) + swzo));              \
    acc[nt_] = MFMA16((Areg), bv_, acc[nt_]); } } while (0)

#define KTSTR(s, Areg) do {                                                     \
  _Pragma("unroll") for (int nt_ = 0; nt_ < 8; ++nt_)                           \
    acc[nt_] = MFMA16((Areg), Bst[s][nt_], acc[nt_]); } while (0)

#define ISSB(s) do { _Pragma("unroll") for (int nt_ = 0; nt_ < 8; ++nt_)        \
    Bst[s][nt_] = gld16_p(strm, (s) * 8192 + (nt_ << 10) + (int)swzo); } while (0)

#define ISSAS(i0) do { _Pragma("unroll") for (int i_ = 0; i_ < 4; ++i_)         \
    AS[(i0) + i_] = gld16_p(selb, ((i0) + i_) * 4096 + abb); } while (0)

#define SCR 155648   // LDS scratch for epilogue transpose (4KB = 4 x 1KB per wave)

__global__ __launch_bounds__(256, 1) void lstm_fused(
    const float* __restrict__ X, const float* __restrict__ Wih0,
    const float* __restrict__ Wih, const float* __restrict__ Whh,
    const float* __restrict__ bih, const float* __restrict__ bhh,
    const float* __restrict__ Wout, const float* __restrict__ bout,
    float* __restrict__ out, char* __restrict__ ws, int rs)
{
  extern __shared__ char lds[];
  const int tid = threadIdx.x;
  const int lane = tid & 63;
  const int wv = tid >> 6;
  const int pp = lane & 15;
  const int lg = lane >> 4;
  const int abb = lg * 1024 + (16 * wv + pp) * 16;
  const uint32_t swzo = (uint32_t)(pp * 64 + lg * 16) ^ (uint32_t)((pp & 7) << 4);
  const int rsm = rs - 1;

  int* progL = (int*)(ws + PL_OFF);
  int* progX = (int*)(ws + PX_OFF);
  int* diag  = (int*)(ws + DIAG_OFF);
  const char* hl = ws + HL_OFF;
  const char* hx = hl + (size_t)10 * rs * 65536;

  int xcd;
  asm volatile("s_getreg_b32 %0, hwreg(HW_REG_XCC_ID)" : "=s"(xcd));
  xcd &= 7;
  if (tid == 0) {
    int s = atomicAdd((int*)(ws + CNT_OFF) + xcd, 1);
    *(int*)lds = s;
  }
  __syncthreads();
  const int slot = __builtin_amdgcn_readfirstlane(*(int*)lds);   // uniform
  __syncthreads();

  // ================= head (XCD 5, slots 0..7), per-wave decoupled ============
  if (xcd == 5) {
    if (slot >= 8) return;
    const int hd = slot, d0 = hd * 8;
    const float* wrow0 = Wout + (size_t)(d0 + wv) * 512;
    const float* wrow1 = Wout + (size_t)(d0 + 4 + wv) * 512;
    const int b = lane;
    const int* pw = progX + (9 * 16 + (lane >> 2)) * 4 + (lane & 3);  // 64 L9 wave-flags
    int* myf = progX + 640 + hd * 4 + wv;
    for (int th = 0; th < 256; ++th) {
      {
        int it = 0; bool bailed = false;
        for (;;) {
          int v = ld_prog(pw);
          if (__ballot(v >= th) == ~0ull) break;
          __builtin_amdgcn_s_sleep(1);
          if (++it > 60000) { bailed = true; break; }
        }
        if (bailed && lane == 0) atomicMax(diag, 10000 + th);
      }
      WAITI(0);
      const char* h9 = unif(hx + (size_t)(4 * rs + ((th + 1) & rsm)) * 65536);
      h8 H0[16], H1[16], H2[16], H3[16];
#pragma unroll
      for (int i = 0; i < 16; ++i) H0[i] = gld16_sc1(h9, i * 1024 + b * 16);
#pragma unroll
      for (int i = 0; i < 16; ++i) H1[i] = gld16_sc1(h9, (16 + i) * 1024 + b * 16);
      float a0 = bout[d0 + wv], a1 = bout[d0 + 4 + wv];
#define KH(kb, H) do { _Pragma("unroll") for (int i_ = 0; i_ < 16; ++i_) {      \
        h8 hv_ = H[i_]; float hf_[8];                                           \
        _Pragma("unroll") for (int j_ = 0; j_ < 8; ++j_) hf_[j_] = (float)hv_[j_]; \
        int kg_ = (kb) + i_;                                                    \
        f4 w0_ = *(const f4*)(wrow0 + kg_ * 8); f4 w1_ = *(const f4*)(wrow0 + kg_ * 8 + 4); \
        a0 += hf_[0]*w0_[0]+hf_[1]*w0_[1]+hf_[2]*w0_[2]+hf_[3]*w0_[3]           \
            + hf_[4]*w1_[0]+hf_[5]*w1_[1]+hf_[6]*w1_[2]+hf_[7]*w1_[3];          \
        f4 u0_ = *(const f4*)(wrow1 + kg_ * 8); f4 u1_ = *(const f4*)(wrow1 + kg_ * 8 + 4); \
        a1 += hf_[0]*u0_[0]+hf_[1]*u0_[1]+hf_[2]*u0_[2]+hf_[3]*u0_[3]           \
            + hf_[4]*u1_[0]+hf_[5]*u1_[1]+hf_[6]*u1_[2]+hf_[7]*u1_[3]; } } while (0)
      WAITI(16); KH(0, H0);
#pragma unroll
      for (int i = 0; i < 16; ++i) H2[i] = gld16_sc1(h9, (32 + i) * 1024 + b * 16);
      WAITI(16); KH(16, H1);
#pragma unroll
      for (int i = 0; i < 16; ++i) H3[i] = gld16_sc1(h9, (48 + i) * 1024 + b * 16);
      WAITI(16); KH(32, H2);
      WAITI(0);  KH(48, H3);
      out[(size_t)b * 16384 + (size_t)th * 64 + d0 + wv] = a0;
      out[(size_t)b * 16384 + (size_t)th * 64 + d0 + 4 + wv] = a1;
      // all h9 loads returned (WAITI(0) above) -> safe to release the slot
      if (lane == 0)
        __hip_atomic_store(myf, th, __ATOMIC_RELAXED, __HIP_MEMORY_SCOPE_AGENT);
    }
    if (hd == 0 && wv == 0 && lane == 0) {
      int dv = ld_prog(diag);
      if (dv != 0) out[0] = 1.0e6f + (float)dv;
    }
    return;
  }
  if (xcd > 5 || slot >= 32) return;

  // ================= layer CUs: XCD k hosts layers 2k, 2k+1 =================
  const int L = 2 * xcd + (slot >= 16);
  const int cl = slot & 15;
  const int hbase = cl * 32;
  const bool oddL = (L & 1) != 0;

  // ---- stage resident weights into LDS ----
  if (L == 0) {
    for (int ch = tid; ch < 9216; ch += 256) {   // 18 r: 0,1=x(Wih0) 2..17=h(Whh0)
      int r = ch >> 9, rem = ch & 511;
      int nt = rem >> 6, l = rem & 63, ppc = l >> 2, lgc = l & 3;
      int k = r * 32 + lgc * 8;
      int row = (nt & 3) * 512 + hbase + ((nt >> 2) << 4) + ppc;
      const float* src = (k < 64) ? (Wih0 + (size_t)row * 64 + k)
                                  : (Whh + (size_t)row * 512 + (k - 64));
      h8 v;
#pragma unroll
      for (int j = 0; j < 8; ++j) v[j] = (_Float16)src[j];
      uint32_t off = (uint32_t)(ppc * 64 + lgc * 16) ^ (uint32_t)((ppc & 7) << 4);
      *(h8*)(lds + ((r * 8 + nt) << 10) + off) = v;
    }
  } else {
    const float* WihL = Wih + (size_t)(L - 1) * 1048576;
    const float* WhhL = Whh + (size_t)L * 1048576;
    for (int ch = tid; ch < 9728; ch += 256) {   // 19 r: 0..3 -> kt0..3, 4..18 -> kt17..31
      int r = ch >> 9, rem = ch & 511;
      int nt = rem >> 6, l = rem & 63, ppc = l >> 2, lgc = l & 3;
      int rkt = r < 4 ? r : r + 13;
      int k = rkt * 32 + lgc * 8;
      int row = (nt & 3) * 512 + hbase + ((nt >> 2) << 4) + ppc;
      const float* src = (k < 512) ? (WihL + (size_t)row * 512 + k)
                                   : (WhhL + (size_t)row * 512 + (k - 512));
      h8 v;
#pragma unroll
      for (int j = 0; j < 8; ++j) v[j] = (_Float16)src[j];
      uint32_t off = (uint32_t)(ppc * 64 + lgc * 16) ^ (uint32_t)((ppc & 7) << 4);
      *(h8*)(lds + ((r * 8 + nt) << 10) + off) = v;
    }
  }
  float biasv[8];
#pragma unroll
  for (int nt = 0; nt < 8; ++nt) {
    int row = (nt & 3) * 512 + hbase + ((nt >> 2) << 4) + pp;
    biasv[nt] = bih[L * 2048 + row] + bhh[L * 2048 + row];
  }
  __syncthreads();   // one-time: weights staged

  // ---- per-wave poll descriptors (all 64 lanes active) ----
  const int fl = (lane >> 2);            // CU index 0..15
  const int fw = (lane & 3);             // wave index 0..3
  const volatile int* pS  = (const volatile int*)(progL + (L * 16 + fl) * 4 + fw);
  const volatile int* pBL = (const volatile int*)(progL + ((L > 0 ? L - 1 : 0) * 16 + fl) * 4 + fw);
  const int*          pBX = progX + ((L > 0 ? L - 1 : 0) * 16 + fl) * 4 + fw;
  const volatile int* pCL = (const volatile int*)(progL + ((L < 9 ? L + 1 : 9) * 16 + fl) * 4 + fw);
  const int*          pCX = (L == 9) ? (progX + 640 + (lane & 31))
                                     : (progX + ((L + 1) * 16 + fl) * 4 + fw);
  const bool cValid = (L != 9) || (lane < 32);
  int* myL = progL + (L * 16 + cl) * 4 + wv;
  int* myX = progX + (L * 16 + cl) * 4 + wv;

  const char* strm = unif(ws + WSTRM_OFF + (size_t)((L - 1) * 16 + cl) * 106496);  // L>=1
  const char* xt = ws + XT_OFF;

  float cv[2][4] = {{0,0,0,0},{0,0,0,0}};

  for (int t = 0; t < 256; ++t) {
    // ---- per-wave poll: self(t-1) + below(t) + guard(t-rsm) ----
    {
      int it = 0; bool bailed = false;
      for (;;) {
        INV_L1();
        int vS = *pS;
        int vB = (L == 0) ? 0x7fffffff : (oddL ? *pBL : ld_prog(pBX));
        int vC;
        if (L == 9)      vC = ld_prog(pCX);
        else if (oddL)   vC = ld_prog(pCX);
        else             vC = *pCL;
        bool ok = (vS >= t - 1) && (vB >= t) && (!cValid || vC >= t - rsm);
        if (__ballot(ok) == ~0ull) break;
        if (++it > 60000) { bailed = true; break; }
        if (it > 4) __builtin_amdgcn_s_sleep(1);
      }
      if (bailed && lane == 0) atomicMax(diag, L * 1000 + t);
    }
    WAITI(0);   // clean per-wave vmcnt before the counted stream

    f4 acc[8];
#pragma unroll
    for (int j = 0; j < 8; ++j) acc[j] = (f4){0.f, 0.f, 0.f, 0.f};

    if (L == 0) {
      const char* selb = unif(hl + (size_t)(t & rsm) * 65536);
      const char* xtb = unif(xt + (size_t)t * 8192);
      h8 X0 = gld16_p(xtb, abb);
      h8 X1 = gld16_p(xtb, 4096 + abb);
      h8 AS[16];
#pragma unroll
      for (int i = 0; i < 16; ++i) AS[i] = gld16_p(selb, i * 4096 + abb);
      WAITI(17); KTRES(0, X0);
      WAITI(16); KTRES(1, X1);
      WAITI(15); KTRES(2, AS[0]);  WAITI(14); KTRES(3, AS[1]);
      WAITI(13); KTRES(4, AS[2]);  WAITI(12); KTRES(5, AS[3]);
      WAITI(11); KTRES(6, AS[4]);  WAITI(10); KTRES(7, AS[5]);
      WAITI(9);  KTRES(8, AS[6]);  WAITI(8);  KTRES(9, AS[7]);
      WAITI(7);  KTRES(10, AS[8]); WAITI(6);  KTRES(11, AS[9]);
      WAITI(5);  KTRES(12, AS[10]); WAITI(4); KTRES(13, AS[11]);
      WAITI(3);  KTRES(14, AS[12]); WAITI(2); KTRES(15, AS[13]);
      WAITI(1);  KTRES(16, AS[14]); WAITI(0); KTRES(17, AS[15]);
    } else {
      const char* botb = unif(oddL
          ? (hl + (size_t)((L - 1) * rs + ((t + 1) & rsm)) * 65536)
          : (hx + (size_t)(((L - 1) >> 1) * rs + ((t + 1) & rsm)) * 65536));
      const char* selb = unif(hl + (size_t)(L * rs + (t & rsm)) * 65536);
      h8 AB[16], AS[16], Bst[13][8];
      if (oddL) {
#pragma unroll
        for (int i = 0; i < 16; ++i) AB[i] = gld16_p(botb, i * 4096 + abb);
      } else {
#pragma unroll
        for (int i = 0; i < 16; ++i) AB[i] = gld16_sc1(botb, i * 4096 + abb);
      }
      ISSB(0); ISSB(1);                                  // out 32
      WAITI(31); KTRES(0, AB[0]); ISSB(2);
      WAITI(38); KTRES(1, AB[1]); ISSB(3);
      WAITI(45); KTRES(2, AB[2]); ISSB(4);
      WAITI(52); KTRES(3, AB[3]); ISSB(5);
      WAITI(40); KTSTR(0, AB[4]); ISSB(6);
      WAITI(40); KTSTR(1, AB[5]); ISSB(7);
      WAITI(40); KTSTR(2, AB[6]); ISSB(8);
      WAITI(40); KTSTR(3, AB[7]); ISSB(9);
      WAITI(40); KTSTR(4, AB[8]); ISSB(10);
      WAITI(40); KTSTR(5, AB[9]); ISSB(11);
      WAITI(40); KTSTR(6, AB[10]); ISSB(12);
      WAITI(40); KTSTR(7, AB[11]); ISSAS(0);
      WAITI(36); KTSTR(8, AB[12]); ISSAS(4);
      WAITI(28); KTSTR(9, AB[13]); ISSAS(8);
      WAITI(20); KTSTR(10, AB[14]); ISSAS(12);
      WAITI(12); KTSTR(11, AB[15]);
      WAITI(4);  KTSTR(12, AS[0]);
      KTRES(4, AS[1]);  KTRES(5, AS[2]);  KTRES(6, AS[3]);
      KTRES(7, AS[4]);  KTRES(8, AS[5]);  KTRES(9, AS[6]);
      KTRES(10, AS[7]); KTRES(11, AS[8]); KTRES(12, AS[9]);
      KTRES(13, AS[10]); KTRES(14, AS[11]);
      WAITI(3); KTRES(15, AS[12]);
      WAITI(2); KTRES(16, AS[13]);
      WAITI(1); KTRES(17, AS[14]);
      WAITI(0); KTRES(18, AS[15]);
    }

    // ---- epilogue: wave-local LDS transpose -> 1 coalesced 16B store/lane ----
    const int scrw = SCR + (wv << 10);
#pragma unroll
    for (int jh = 0; jh < 2; ++jh) {
      const int hgl = jh * 16 + pp;
#pragma unroll
      for (int r = 0; r < 4; ++r) {
        float gi = sigm(acc[4*jh+0][r] + biasv[4*jh+0]);
        float gf = sigm(acc[4*jh+1][r] + biasv[4*jh+1]);
        float gg = tanh_f(acc[4*jh+2][r] + biasv[4*jh+2]);
        float go = sigm(acc[4*jh+3][r] + biasv[4*jh+3]);
        float cc = gf * cv[jh][r] + gi * gg;
        cv[jh][r] = cc;
        float hh = go * tanh_f(cc);
        // wave-local region: [hgl>>3 block:256B][row 4lg+r:16B][hgl&7:2B]
        *(_Float16*)(lds + scrw + ((hgl >> 3) << 8) + ((4 * lg + r) << 4) + ((hgl & 7) << 1))
            = (_Float16)hh;
      }
    }
    // wave-local read-back (compiler orders via lgkmcnt)
    {
      h8 vv = *(const h8*)(lds + scrw + ((lane >> 4) << 8) + ((lane & 15) << 4));
      const int goff = (((hbase >> 3) + (lane >> 4)) << 10) + (16 * wv + (lane & 15)) * 16;
      const char* HdL = unif(hl + (size_t)(L * rs + ((t + 1) & rsm)) * 65536);
      gst16_p(HdL, goff, vv);                            // plain -> home L2 (first)
      if (oddL) {
        const char* HdX = unif(hx + (size_t)((L >> 1) * rs + ((t + 1) & rsm)) * 65536);
        gst16_sc1(HdX, goff, vv);                        // coherent -> L3 (second)
      }
    }
    if (oddL) {
      WAITI(1);                       // this wave's plain store L2-acked
      if (lane == 0) {
        *(volatile int*)myL = t;      // early intra-XCD release
        __builtin_amdgcn_sched_barrier(0);
      }
      WAITI(0);                       // sc1 store L3-acked
      if (lane == 0)
        __hip_atomic_store(myX, t, __ATOMIC_RELAXED, __HIP_MEMORY_SCOPE_AGENT);
    } else {
      WAITI(0);
      if (lane == 0) {
        *(volatile int*)myL = t;
        __hip_atomic_store(myX, t, __ATOMIC_RELAXED, __HIP_MEMORY_SCOPE_AGENT);
      }
    }
  }
}

// ---------------- host ----------------
extern "C" void kernel_launch(void* const* d_in, const int* in_sizes, int n_in,
                              void* d_out, int out_size, void* d_ws, size_t ws_size,
                              hipStream_t stream) {
  const float* X    = (const float*)d_in[0];
  const float* Wih0 = (const float*)d_in[1];
  const float* Wih  = (const float*)d_in[2];
  const float* Whh  = (const float*)d_in[3];
  const float* bihp = (const float*)d_in[4];
  const float* bhhp = (const float*)d_in[5];
  const float* Wout = (const float*)d_in[6];
  const float* bout = (const float*)d_in[7];
  float* out = (float*)d_out;
  char* ws = (char*)d_ws;
  (void)in_sizes; (void)n_in; (void)out_size;

  // adaptive ring depth: 16 if ws allows, else 8
  int rs = 16;
  size_t need = HL_OFF + 15ull * rs * 65536;   // hl(10) + hx(5)
  if (ws_size < need) { rs = 8; need = HL_OFF + 15ull * rs * 65536; }
  if (ws_size < need) return;   // visible failure, no corruption

  hipFuncSetAttribute((const void*)lstm_fused,
                      hipFuncAttributeMaxDynamicSharedMemorySize, 163840);

  zero_kernel<<<646, 256, 0, stream>>>(ws, rs);
  xprep_kernel<<<512, 256, 0, stream>>>(X, ws);
  wsprep_kernel<<<3744, 256, 0, stream>>>(Wih, Whh, ws);
  lstm_fused<<<256, 256, 163840, stream>>>(X, Wih0, Wih, Whh, bihp, bhhp,
                                           Wout, bout, out, ws, rs);
}

// Round 15
// 2912.387 us; speedup vs baseline: 1.3362x; 1.3362x over previous
//
#include <hip/hip_runtime.h>
#include <hip/hip_fp16.h>
#include <stdint.h>

typedef _Float16 h8 __attribute__((ext_vector_type(8)));
typedef float f4 __attribute__((ext_vector_type(4)));

#define MFMA16(a,b,c) __builtin_amdgcn_mfma_f32_16x16x32_f16((a),(b),(c),0,0,0)

// ---------------- ws memory map (R9-proven layout) ----------------
constexpr size_t XT_OFF = 0;                       // [256 t][8 kg][64 b][8h] fp16
constexpr size_t XT_BYTES = 256ull * 4096 * 2;
constexpr size_t HL_OFF = XT_OFF + XT_BYTES;       // plain h rings [10 L][8 slot][64KB]
constexpr size_t HL_BYTES = 10ull * 8 * 65536;
constexpr size_t HX_OFF = HL_OFF + HL_BYTES;       // sc1 h rings (odd L) [5][8][64KB]
constexpr size_t HX_BYTES = 5ull * 8 * 65536;
constexpr size_t WSTRM_OFF = HX_OFF + HX_BYTES;    // streamed W frags [144 cu][13 s][8 nt][1KB]
constexpr size_t WSTRM_BYTES = 144ull * 106496;
constexpr size_t PX_OFF = WSTRM_OFF + WSTRM_BYTES; // progX[168] sc1 flags
constexpr size_t CNT_OFF = PX_OFF + 1024;
constexpr size_t DIAG_OFF = CNT_OFF + 64;
constexpr size_t WS_NEED = DIAG_OFF + 64;

#define SCR 155648   // LDS scratch for epilogue transpose (4KB)

// force a pointer into SGPRs (uniform) for inline-asm "s" operands
__device__ __forceinline__ const char* unif(const void* p) {
  uint64_t u = (uint64_t)p;
  uint32_t lo = __builtin_amdgcn_readfirstlane((uint32_t)u);
  uint32_t hi = __builtin_amdgcn_readfirstlane((uint32_t)(u >> 32));
  return (const char*)(((uint64_t)hi << 32) | lo);
}

// ---------------- asm load/store helpers (hand-counted vmcnt stream) --------
__device__ __forceinline__ h8 gld16_p(const void* base, int voff) {
  h8 v; asm volatile("global_load_dwordx4 %0, %1, %2" : "=v"(v) : "v"(voff), "s"(base)); return v;
}
__device__ __forceinline__ h8 gld16_sc1(const void* base, int voff) {
  h8 v; asm volatile("global_load_dwordx4 %0, %1, %2 sc1" : "=v"(v) : "v"(voff), "s"(base)); return v;
}
__device__ __forceinline__ void gst16_sc1(const void* base, int voff, h8 v) {
  asm volatile("global_store_dwordx4 %0, %1, %2 sc1" :: "v"(voff), "v"(v), "s"(base) : "memory");
}
#define WAITI(n) do { asm volatile("s_waitcnt vmcnt(" #n ")" ::: "memory"); \
                      __builtin_amdgcn_sched_barrier(0); } while (0)

__device__ __forceinline__ int ld_prog(const int* p) {
  return __hip_atomic_load(p, __ATOMIC_RELAXED, __HIP_MEMORY_SCOPE_AGENT);
}
__device__ __forceinline__ void st_prog(int* p, int v) {
  __hip_atomic_store(p, v, __ATOMIC_RELAXED, __HIP_MEMORY_SCOPE_AGENT);
  __builtin_amdgcn_sched_barrier(0);
}
#define INV_L1() asm volatile("buffer_inv sc0\n\ts_waitcnt vmcnt(0)" ::: "memory")

__device__ __forceinline__ float sigm(float x) { return __fdividef(1.f, 1.f + __expf(-x)); }
__device__ __forceinline__ float tanh_f(float x) { return 1.f - __fdividef(2.f, __expf(2.f*x) + 1.f); }

// ---------------- prep kernels ----------------
__global__ __launch_bounds__(256) void zero_kernel(char* ws) {
  int i = blockIdx.x * 256 + threadIdx.x;
  if (i < 163840) {
    int layer = i >> 14, w = i & 16383;
    ((int*)(ws + HL_OFF))[(size_t)layer * 8 * 16384 + w] = 0;
  } else {
    int j = i - 163840;
    if (j < 168) ((int*)(ws + PX_OFF))[j] = -1;
    else if (j < 176) ((int*)(ws + CNT_OFF))[j - 168] = 0;
    else if (j == 176) ((int*)(ws + DIAG_OFF))[0] = 0;
  }
}

__global__ __launch_bounds__(256) void xprep_kernel(const float* __restrict__ X, char* ws) {
  int u = blockIdx.x * 256 + threadIdx.x;
  if (u >= 131072) return;
  int t = u >> 9, rem = u & 511, kg = rem >> 6, b = rem & 63;
  const float* src = X + ((size_t)b * 256 + t) * 64 + kg * 8;
  h8 v;
#pragma unroll
  for (int j = 0; j < 8; ++j) v[j] = (_Float16)src[j];
  *(h8*)(ws + XT_OFF + (size_t)u * 16) = v;
}

// pack streamed kt 4..16 (s=0..12) into per-lane fragment layout
__global__ __launch_bounds__(256) void wsprep_kernel(const float* __restrict__ Wih,
                                                     const float* __restrict__ Whh, char* ws) {
  int u = blockIdx.x * 256 + threadIdx.x;
  if (u >= 144 * 6656) return;
  int cu = u / 6656, rem = u % 6656;
  int s = rem / 512, rem2 = rem % 512;
  int nt = rem2 >> 6, l = rem2 & 63;
  int ppc = l >> 2, lgc = l & 3;
  int L = 1 + cu / 16, cl = cu % 16, hbase = cl * 32;
  int kt = 4 + s, k = kt * 32 + lgc * 8;
  int row = (nt & 3) * 512 + hbase + ((nt >> 2) << 4) + ppc;
  const float* src = (k < 512) ? (Wih + (size_t)(L - 1) * 1048576 + (size_t)row * 512 + k)
                               : (Whh + (size_t)L * 1048576 + (size_t)row * 512 + (k - 512));
  h8 v;
#pragma unroll
  for (int j = 0; j < 8; ++j) v[j] = (_Float16)src[j];
  uint32_t off = (uint32_t)(ppc * 64 + lgc * 16) ^ (uint32_t)((ppc & 7) << 4);
  *(h8*)(ws + WSTRM_OFF + (size_t)cu * 106496 + (size_t)s * 8192 + (size_t)nt * 1024 + off) = v;
}

// ---------------- main persistent kernel ----------------
#define KTRES(r, Areg) do {                                                     \
  _Pragma("unroll") for (int nt_ = 0; nt_ < 8; ++nt_) {                         \
    h8 bv_ = *(const h8*)(lds + ((((r) * 8 + nt_) << 10) + swzo));              \
    acc[nt_] = MFMA16((Areg), bv_, acc[nt_]); } } while (0)

#define KTSTR(s, Areg) do {                                                     \
  _Pragma("unroll") for (int nt_ = 0; nt_ < 8; ++nt_)                           \
    acc[nt_] = MFMA16((Areg), Bst[s][nt_], acc[nt_]); } while (0)

#define ISSB(s) do { _Pragma("unroll") for (int nt_ = 0; nt_ < 8; ++nt_)        \
    Bst[s][nt_] = gld16_p(strm, (s) * 8192 + (nt_ << 10) + (int)swzo); } while (0)

#define ISSAS(i0) do { _Pragma("unroll") for (int i_ = 0; i_ < 4; ++i_)         \
    AS[(i0) + i_] = gld16_p(selb, ((i0) + i_) * 4096 + abb); } while (0)

__global__ __launch_bounds__(256, 1) void lstm_fused(
    const float* __restrict__ X, const float* __restrict__ Wih0,
    const float* __restrict__ Wih, const float* __restrict__ Whh,
    const float* __restrict__ bih, const float* __restrict__ bhh,
    const float* __restrict__ Wout, const float* __restrict__ bout,
    float* __restrict__ out, char* __restrict__ ws)
{
  extern __shared__ char lds[];
  const int tid = threadIdx.x;
  const int lane = tid & 63;
  const int wv = tid >> 6;
  const int pp = lane & 15;
  const int lg = lane >> 4;
  const int abb = lg * 1024 + (16 * wv + pp) * 16;
  const uint32_t swzo = (uint32_t)(pp * 64 + lg * 16) ^ (uint32_t)((pp & 7) << 4);

  int* progX = (int*)(ws + PX_OFF);
  int* diag  = (int*)(ws + DIAG_OFF);
  const char* hl = ws + HL_OFF;
  const char* hx = ws + HX_OFF;

  int xcd;
  asm volatile("s_getreg_b32 %0, hwreg(HW_REG_XCC_ID)" : "=s"(xcd));
  xcd &= 7;
  if (tid == 0) {
    int s = atomicAdd((int*)(ws + CNT_OFF) + xcd, 1);
    *(int*)lds = s;
  }
  __syncthreads();
  const int slot = __builtin_amdgcn_readfirstlane(*(int*)lds);   // explicitly uniform
  __syncthreads();

  // ================= head (XCD 5, slots 0..7) =================
  if (xcd == 5) {
    if (slot >= 8) return;
    const int hd = slot, d0 = hd * 8;
    const float* wrow0 = Wout + (size_t)(d0 + wv) * 512;
    const float* wrow1 = Wout + (size_t)(d0 + 4 + wv) * 512;
    const int b = lane;
    const bool pv = lane < 16;
    const int* pw = progX + 144 + (lane & 15);
    for (int th = 0; th < 256; ++th) {
      if (wv == 0) {
        int it = 0; bool bailed = false;
        for (;;) {
          int v = ld_prog(pw);
          if (__ballot(!pv || v >= th) == ~0ull) break;
          __builtin_amdgcn_s_sleep(1);
          if (++it > 60000) { bailed = true; break; }
        }
        if (bailed && lane == 0) atomicMax(diag, 10000 + th);
      }
      __builtin_amdgcn_s_barrier();
      const char* h9 = unif(hx + (size_t)(4 * 8 + ((th + 1) & 7)) * 65536);
      h8 H0[16], H1[16], H2[16], H3[16];
#pragma unroll
      for (int i = 0; i < 16; ++i) H0[i] = gld16_sc1(h9, i * 1024 + b * 16);
#pragma unroll
      for (int i = 0; i < 16; ++i) H1[i] = gld16_sc1(h9, (16 + i) * 1024 + b * 16);
      float a0 = bout[d0 + wv], a1 = bout[d0 + 4 + wv];
#define KH(kb, H) do { _Pragma("unroll") for (int i_ = 0; i_ < 16; ++i_) {      \
        h8 hv_ = H[i_]; float hf_[8];                                           \
        _Pragma("unroll") for (int j_ = 0; j_ < 8; ++j_) hf_[j_] = (float)hv_[j_]; \
        int kg_ = (kb) + i_;                                                    \
        f4 w0_ = *(const f4*)(wrow0 + kg_ * 8); f4 w1_ = *(const f4*)(wrow0 + kg_ * 8 + 4); \
        a0 += hf_[0]*w0_[0]+hf_[1]*w0_[1]+hf_[2]*w0_[2]+hf_[3]*w0_[3]           \
            + hf_[4]*w1_[0]+hf_[5]*w1_[1]+hf_[6]*w1_[2]+hf_[7]*w1_[3];          \
        f4 u0_ = *(const f4*)(wrow1 + kg_ * 8); f4 u1_ = *(const f4*)(wrow1 + kg_ * 8 + 4); \
        a1 += hf_[0]*u0_[0]+hf_[1]*u0_[1]+hf_[2]*u0_[2]+hf_[3]*u0_[3]           \
            + hf_[4]*u1_[0]+hf_[5]*u1_[1]+hf_[6]*u1_[2]+hf_[7]*u1_[3]; } } while (0)
      WAITI(16); KH(0, H0);
#pragma unroll
      for (int i = 0; i < 16; ++i) H2[i] = gld16_sc1(h9, (32 + i) * 1024 + b * 16);
      WAITI(16); KH(16, H1);
#pragma unroll
      for (int i = 0; i < 16; ++i) H3[i] = gld16_sc1(h9, (48 + i) * 1024 + b * 16);
      WAITI(16); KH(32, H2);
      WAITI(0);  KH(48, H3);
      out[(size_t)b * 16384 + (size_t)th * 64 + d0 + wv] = a0;
      out[(size_t)b * 16384 + (size_t)th * 64 + d0 + 4 + wv] = a1;
      __syncthreads();
      if (tid == 0) st_prog(progX + 160 + hd, th);
    }
    if (hd == 0 && tid == 0) {
      int dv = ld_prog(diag);
      if (dv != 0) out[0] = 1.0e6f + (float)dv;
    }
    return;
  }
  if (xcd > 5 || slot >= 32) return;

  // ================= layer CUs: XCD k hosts layers 2k, 2k+1 =================
  const int L = 2 * xcd + (slot >= 16);
  const int cl = slot & 15;
  const int hbase = cl * 32;
  const bool oddL = (L & 1) != 0;

  // ---- stage resident weights into LDS ----
  if (L == 0) {
    for (int ch = tid; ch < 9216; ch += 256) {   // 18 r: 0,1=x(Wih0) 2..17=h(Whh0)
      int r = ch >> 9, rem = ch & 511;
      int nt = rem >> 6, l = rem & 63, ppc = l >> 2, lgc = l & 3;
      int k = r * 32 + lgc * 8;
      int row = (nt & 3) * 512 + hbase + ((nt >> 2) << 4) + ppc;
      const float* src = (k < 64) ? (Wih0 + (size_t)row * 64 + k)
                                  : (Whh + (size_t)row * 512 + (k - 64));
      h8 v;
#pragma unroll
      for (int j = 0; j < 8; ++j) v[j] = (_Float16)src[j];
      uint32_t off = (uint32_t)(ppc * 64 + lgc * 16) ^ (uint32_t)((ppc & 7) << 4);
      *(h8*)(lds + ((r * 8 + nt) << 10) + off) = v;
    }
  } else {
    const float* WihL = Wih + (size_t)(L - 1) * 1048576;
    const float* WhhL = Whh + (size_t)L * 1048576;
    for (int ch = tid; ch < 9728; ch += 256) {   // 19 r: 0..3 -> kt0..3, 4..18 -> kt17..31
      int r = ch >> 9, rem = ch & 511;
      int nt = rem >> 6, l = rem & 63, ppc = l >> 2, lgc = l & 3;
      int rkt = r < 4 ? r : r + 13;
      int k = rkt * 32 + lgc * 8;
      int row = (nt & 3) * 512 + hbase + ((nt >> 2) << 4) + ppc;
      const float* src = (k < 512) ? (WihL + (size_t)row * 512 + k)
                                   : (WhhL + (size_t)row * 512 + (k - 512));
      h8 v;
#pragma unroll
      for (int j = 0; j < 8; ++j) v[j] = (_Float16)src[j];
      uint32_t off = (uint32_t)(ppc * 64 + lgc * 16) ^ (uint32_t)((ppc & 7) << 4);
      *(h8*)(lds + ((r * 8 + nt) << 10) + off) = v;
    }
  }
  float biasv[8];
#pragma unroll
  for (int nt = 0; nt < 8; ++nt) {
    int row = (nt & 3) * 512 + hbase + ((nt >> 2) << 4) + pp;
    biasv[nt] = bih[L * 2048 + row] + bhh[L * 2048 + row];
  }
  __syncthreads();

  // ---- poll descriptors ----
  const int jl = lane & 15;
  const int* pw = progX; bool pv = false; int dlt = 0;
  if (lane < 16)      { pv = true; pw = progX + L * 16 + jl; dlt = -1; }
  else if (lane < 32) { if (L > 0) { pv = true; pw = progX + (L - 1) * 16 + jl; dlt = 0; } }
  else if (lane < 48) {
    dlt = -7;
    if (L == 9) { if (jl < 8) { pv = true; pw = progX + 160 + jl; } }
    else        { pv = true; pw = progX + (L + 1) * 16 + jl; }
  }

  const char* strm = unif(ws + WSTRM_OFF + (size_t)((L - 1) * 16 + cl) * 106496);  // L>=1
  const char* xt = ws + XT_OFF;

  float cv[2][4] = {{0,0,0,0},{0,0,0,0}};

  for (int t = 0; t < 256; ++t) {
    if (wv == 0) {
      int it = 0; bool bailed = false;
      for (;;) {
        int v = ld_prog(pw);
        if (__ballot(!pv || v >= t + dlt) == ~0ull) break;
        __builtin_amdgcn_s_sleep(1);
        if (++it > 60000) { bailed = true; break; }
      }
      if (bailed && lane == 0) atomicMax(diag, L * 1000 + t);
      INV_L1();
    }
    __builtin_amdgcn_s_barrier();

    f4 acc[8];
#pragma unroll
    for (int j = 0; j < 8; ++j) acc[j] = (f4){0.f, 0.f, 0.f, 0.f};

    if (L == 0) {
      const char* selb = unif(hl + (size_t)(t & 7) * 65536);
      const char* xtb = unif(xt + (size_t)t * 8192);
      h8 X0 = gld16_p(xtb, abb);
      h8 X1 = gld16_p(xtb, 4096 + abb);
      h8 AS[16];
#pragma unroll
      for (int i = 0; i < 16; ++i) AS[i] = gld16_p(selb, i * 4096 + abb);
      WAITI(17); KTRES(0, X0);
      WAITI(16); KTRES(1, X1);
      WAITI(15); KTRES(2, AS[0]);  WAITI(14); KTRES(3, AS[1]);
      WAITI(13); KTRES(4, AS[2]);  WAITI(12); KTRES(5, AS[3]);
      WAITI(11); KTRES(6, AS[4]);  WAITI(10); KTRES(7, AS[5]);
      WAITI(9);  KTRES(8, AS[6]);  WAITI(8);  KTRES(9, AS[7]);
      WAITI(7);  KTRES(10, AS[8]); WAITI(6);  KTRES(11, AS[9]);
      WAITI(5);  KTRES(12, AS[10]); WAITI(4); KTRES(13, AS[11]);
      WAITI(3);  KTRES(14, AS[12]); WAITI(2); KTRES(15, AS[13]);
      WAITI(1);  KTRES(16, AS[14]); WAITI(0); KTRES(17, AS[15]);
    } else {
      const char* botb = unif(oddL
          ? (hl + (size_t)((L - 1) * 8 + ((t + 1) & 7)) * 65536)
          : (hx + (size_t)(((L - 1) >> 1) * 8 + ((t + 1) & 7)) * 65536));
      const char* selb = unif(hl + (size_t)(L * 8 + (t & 7)) * 65536);
      h8 AB[16], AS[16], Bst[13][8];
      if (oddL) {
#pragma unroll
        for (int i = 0; i < 16; ++i) AB[i] = gld16_p(botb, i * 4096 + abb);
      } else {
#pragma unroll
        for (int i = 0; i < 16; ++i) AB[i] = gld16_sc1(botb, i * 4096 + abb);
      }
      ISSB(0); ISSB(1);                                  // out 32
      WAITI(31); KTRES(0, AB[0]); ISSB(2);
      WAITI(38); KTRES(1, AB[1]); ISSB(3);
      WAITI(45); KTRES(2, AB[2]); ISSB(4);
      WAITI(52); KTRES(3, AB[3]); ISSB(5);
      WAITI(40); KTSTR(0, AB[4]); ISSB(6);
      WAITI(40); KTSTR(1, AB[5]); ISSB(7);
      WAITI(40); KTSTR(2, AB[6]); ISSB(8);
      WAITI(40); KTSTR(3, AB[7]); ISSB(9);
      WAITI(40); KTSTR(4, AB[8]); ISSB(10);
      WAITI(40); KTSTR(5, AB[9]); ISSB(11);
      WAITI(40); KTSTR(6, AB[10]); ISSB(12);
      WAITI(40); KTSTR(7, AB[11]); ISSAS(0);
      WAITI(36); KTSTR(8, AB[12]); ISSAS(4);
      WAITI(28); KTSTR(9, AB[13]); ISSAS(8);
      WAITI(20); KTSTR(10, AB[14]); ISSAS(12);
      WAITI(12); KTSTR(11, AB[15]);
      WAITI(4);  KTSTR(12, AS[0]);
      KTRES(4, AS[1]);  KTRES(5, AS[2]);  KTRES(6, AS[3]);
      KTRES(7, AS[4]);  KTRES(8, AS[5]);  KTRES(9, AS[6]);
      KTRES(10, AS[7]); KTRES(11, AS[8]); KTRES(12, AS[9]);
      KTRES(13, AS[10]); KTRES(14, AS[11]);
      WAITI(3); KTRES(15, AS[12]);
      WAITI(2); KTRES(16, AS[13]);
      WAITI(1); KTRES(17, AS[14]);
      WAITI(0); KTRES(18, AS[15]);
    }

    // ---- epilogue: gates -> LDS transpose -> wide coalesced stores ----
    const int brow = 16 * wv + 4 * lg;
#pragma unroll
    for (int jh = 0; jh < 2; ++jh) {
      const int hgl = jh * 16 + pp;
#pragma unroll
      for (int r = 0; r < 4; ++r) {
        float gi = sigm(acc[4*jh+0][r] + biasv[4*jh+0]);
        float gf = sigm(acc[4*jh+1][r] + biasv[4*jh+1]);
        float gg = tanh_f(acc[4*jh+2][r] + biasv[4*jh+2]);
        float go = sigm(acc[4*jh+3][r] + biasv[4*jh+3]);
        float cc = gf * cv[jh][r] + gi * gg;
        cv[jh][r] = cc;
        float hh = go * tanh_f(cc);
        *(_Float16*)(lds + SCR + ((hgl >> 3) << 10) + (brow + r) * 16 + ((hgl & 7) << 1))
            = (_Float16)hh;
      }
    }
    __syncthreads();
    {
      const int kg_l = tid >> 6, b = tid & 63;
      h8 vv = *(const h8*)(lds + SCR + tid * 16);
      const int goff = (((hbase >> 3) + kg_l) << 10) + b * 16;
      const char* HdL = unif(hl + (size_t)(L * 8 + ((t + 1) & 7)) * 65536);
      // plain -> home L2
      asm volatile("global_store_dwordx4 %0, %1, %2" :: "v"(goff), "v"(vv), "s"(HdL) : "memory");
      if (oddL) {
        const char* HdX = unif(hx + (size_t)((L >> 1) * 8 + ((t + 1) & 7)) * 65536);
        gst16_sc1(HdX, goff, vv);                        // coherent -> L3
      }
    }
    asm volatile("s_waitcnt vmcnt(0)" ::: "memory");     // all h stores acked
    __syncthreads();
    if (tid == 0) st_prog(progX + L * 16 + cl, t);
  }
}

// ---------------- host ----------------
extern "C" void kernel_launch(void* const* d_in, const int* in_sizes, int n_in,
                              void* d_out, int out_size, void* d_ws, size_t ws_size,
                              hipStream_t stream) {
  const float* X    = (const float*)d_in[0];
  const float* Wih0 = (const float*)d_in[1];
  const float* Wih  = (const float*)d_in[2];
  const float* Whh  = (const float*)d_in[3];
  const float* bihp = (const float*)d_in[4];
  const float* bhhp = (const float*)d_in[5];
  const float* Wout = (const float*)d_in[6];
  const float* bout = (const float*)d_in[7];
  float* out = (float*)d_out;
  char* ws = (char*)d_ws;
  (void)in_sizes; (void)n_in; (void)out_size;
  if (ws_size < WS_NEED) return;

  hipFuncSetAttribute((const void*)lstm_fused,
                      hipFuncAttributeMaxDynamicSharedMemorySize, 163840);

  zero_kernel<<<642, 256, 0, stream>>>(ws);
  xprep_kernel<<<512, 256, 0, stream>>>(X, ws);
  wsprep_kernel<<<3744, 256, 0, stream>>>(Wih, Whh, ws);
  lstm_fused<<<256, 256, 163840, stream>>>(X, Wih0, Wih, Whh, bihp, bhhp,
                                           Wout, bout, out, ws);
}